// Round 9
// baseline (149.296 us; speedup 1.0000x reference)
//
#include <hip/hip_runtime.h>
#include <hip/hip_fp16.h>

#define NBLK 256
#define NT   512
#define FPAD 16   // 64 B per flag slot
#define SMEM_BYTES 140288   // 35072 floats

typedef _Float16 h2_t  __attribute__((ext_vector_type(2)));
typedef _Float16 half8 __attribute__((ext_vector_type(8)));
typedef float    f32x4 __attribute__((ext_vector_type(4)));

// pack two fp32 -> fp16 pair (RNE)
__device__ __forceinline__ unsigned pkh(float a, float b) {
    const __half2 h = __floats2half2_rn(a, b);
    return __builtin_bit_cast(unsigned, h);
}
// fp16-pair dot product with fp32 accumulate (v_dot2_f32_f16) — U2 matvec only
__device__ __forceinline__ float fdot2(unsigned w, unsigned a, float c) {
#if __has_builtin(__builtin_amdgcn_fdot2)
    return __builtin_amdgcn_fdot2(__builtin_bit_cast(h2_t, w),
                                  __builtin_bit_cast(h2_t, a), c, false);
#else
    const float2 fw = __half22float2(__builtin_bit_cast(__half2, w));
    const float2 fa = __half22float2(__builtin_bit_cast(__half2, a));
    return c + fw.x * fa.x + fw.y * fa.y;
#endif
}

__device__ __forceinline__ half8 ldw(const unsigned* p) {
    return __builtin_bit_cast(half8, *(const uint4*)p);
}
__device__ __forceinline__ f32x4 MF(half8 a, half8 b, f32x4 c) {
    return __builtin_amdgcn_mfma_f32_16x16x32_f16(a, b, c, 0, 0, 0);
}

// ---- validated arrive + block0-fanout global wait (pack barrier only) ----
__device__ __forceinline__ void bar_arrive(int n, unsigned* flags, int lid) {
    __syncthreads();
    if (threadIdx.x == 0)
        __hip_atomic_store(&flags[lid * FPAD], (unsigned)n, __ATOMIC_RELEASE,
                           __HIP_MEMORY_SCOPE_AGENT);
}
__device__ __forceinline__ void bar_wait_global(int n, unsigned* flags, unsigned* rel,
                                                int bid, bool fence) {
    if (bid == 0) {
        if (threadIdx.x < NBLK) {
            while ((int)__hip_atomic_load(&flags[threadIdx.x * FPAD],
                                          __ATOMIC_RELAXED,
                                          __HIP_MEMORY_SCOPE_AGENT) < n)
                __builtin_amdgcn_s_sleep(1);
        }
        __syncthreads();
        if (threadIdx.x < 16)
            __hip_atomic_store(&rel[(n * 16 + threadIdx.x) * FPAD], (unsigned)n,
                               __ATOMIC_RELEASE, __HIP_MEMORY_SCOPE_AGENT);
    } else {
        if (threadIdx.x == 0) {
            while ((int)__hip_atomic_load(&rel[(n * 16 + (bid & 15)) * FPAD],
                                          __ATOMIC_RELAXED,
                                          __HIP_MEMORY_SCOPE_AGENT) < n)
                __builtin_amdgcn_s_sleep(1);
        }
    }
    if (fence) __builtin_amdgcn_fence(__ATOMIC_ACQUIRE, "agent");
    __syncthreads();
}

// MFMA-pack (matrices 0..8): uint idx = (t*8+kc)*256 + (g*16+lc)*4 + sl —
// lane l = g*16+lc holds col t*16+lc, k = kc*32 + g*8 + {0..7}. Identical k-map
// to the A-staging read (validated R5/R7) -> internal k relabeling cancels.
// Old pack (matrices 9..11, U2 fdot2 path): idx = (k>>3)*1024 + c*4 + ((k>>1)&3).

__global__ __launch_bounds__(NT, 2)   // 256-VGPR cap (R5/R7-validated choice)
void fused_k(
    const float* __restrict__ feat,   // [16][128][256]
    const float* __restrict__ mask,   // [16][128]
    const float* __restrict__ aggW,   // [3][256][256]
    const float* __restrict__ aggB,   // [3][256]
    const float* __restrict__ attnW,  // [3][256][512]
    const float* __restrict__ updW,   // [3][256][512]
    const float* __restrict__ updB,   // [3][256]
    unsigned* __restrict__ WtH,       // 12 * 32768 uints (fp16-pair packed)
    unsigned* flags, unsigned* rel,
    float* __restrict__ out)
{
    // A-layout (validated R5/R7): row r (0..127), k-pair p2 (0..127):
    //   uint idx = r*132 + p2; A-frag read lane l, chunk kc:
    //   ds_read_b128 at (rt*16 + (l&15))*132 + kc*16 + (l>>4)*4.
    extern __shared__ float lds[];
    unsigned* hid_uu = (unsigned*)lds;             // [0,16896)      128 x 132
    unsigned* x_uu   = (unsigned*)lds + 16896;     // [16896,33792)  128 x 132
    float*    S      = lds + 33792;                // [33792,34304)  U2 partials
    float*    accl   = lds + 34304;                // [34304,34560)
    float*    aggl32 = lds + 34560;                // [34560,34816)
    unsigned* aggh   = (unsigned*)lds + 34816;     // [34816,34944)
    float*    msk    = lds + 34944;                // [34944,35072)

    const int bid = blockIdx.x;
    const int tid = threadIdx.x;
    const int c   = tid & 255;
    const int rq  = tid >> 8;                 // 0..1 (U2 k-split)
    const int wid = tid >> 6, lane = tid & 63;
    const int lr  = lane & 15, lg = lane >> 4;
    // XCD co-location: 16 blocks of a batch share bid%8 (round-robin heuristic).
    const int b   = 2 * (bid & 7) + ((bid >> 3) & 1);
    const int jj  = bid >> 4;
    const int lid = b * 16 + jj;
    const int row0 = b * 128 + jj * 8;        // this block's OWN output rows

    // ---- P0a: stage FULL batch hid0 = fp16(feat*mask) into A-layout
    {
        const float* fb = feat + (size_t)b * 128 * 256;
        #pragma unroll
        for (int it = 0; it < 16; ++it) {
            const int j = it * NT + tid;              // 0..8191
            const int r = j >> 6, p4 = j & 63;
            const float4 f = *(const float4*)(fb + (size_t)r * 256 + p4 * 4);
            const float mv = mask[b * 128 + r];
            hid_uu[r * 132 + p4 * 2]     = pkh(f.x * mv, f.y * mv);
            hid_uu[r * 132 + p4 * 2 + 1] = pkh(f.z * mv, f.w * mv);
        }
        if (tid < 128) msk[tid] = mask[b * 128 + tid];
    }

    // ---- P0b: transpose + fp16-pack 12 weight mats (blocks 0..191)
    // Write loop is R7-VERBATIM (R8's re-indexed version read unwritten Tl rows).
    if (bid < 192) {
        float (*Tl)[65] = (float (*)[65])(lds + 16896);   // overlay in x_uu (dead)
        const int m = bid >> 4, t = bid & 15, tr = t >> 2, tc = t & 3;
        const float* src; int stride, off;
        if (m < 3)      { src = aggW  + (size_t)m * 65536;        stride = 256; off = 0;   }
        else if (m < 6) { src = attnW + (size_t)(m - 3) * 131072; stride = 512; off = 0;   }
        else if (m < 9) { src = updW  + (size_t)(m - 6) * 131072; stride = 512; off = 0;   }
        else            { src = updW  + (size_t)(m - 9) * 131072; stride = 512; off = 256; }
        unsigned* dstu = WtH + (size_t)m * 32768;
        #pragma unroll
        for (int it = 0; it < 2; ++it) {
            const int j = it * 512 + tid, row = j >> 4, q = (j & 15) * 4;
            const float4 v = *(const float4*)(src + (size_t)(tr * 64 + row) * stride + off + tc * 64 + q);
            Tl[row][q + 0] = v.x; Tl[row][q + 1] = v.y;
            Tl[row][q + 2] = v.z; Tl[row][q + 3] = v.w;
        }
        __syncthreads();
        #pragma unroll
        for (int it = 0; it < 4; ++it) {
            const int j = it * 512 + tid, cl = j >> 5, pr = j & 31;
            const unsigned val = pkh(Tl[cl][pr * 2], Tl[cl][pr * 2 + 1]);
            const int C = tr * 64 + cl, P = tc * 32 + pr;
            size_t idx;
            if (m < 9) {   // MFMA B-fragment pack
                const int ttn = C >> 4, lc = C & 15;
                const int kc = P >> 4, g = (P >> 2) & 3, sl = P & 3;
                idx = (size_t)((ttn * 8 + kc) * 256 + (g * 16 + lc) * 4 + sl);
            } else {       // old pack (U2 fdot2 path)
                idx = (size_t)(P >> 2) * 1024 + (size_t)C * 4 + (P & 3);
            }
            dstu[idx] = val;
        }
    }
    bar_arrive(1, flags, lid);
    bar_wait_global(1, flags, rel, bid, true);   // only barrier in the kernel

    const int ct0 = wid * 2, ct1 = wid * 2 + 1;

    // ================= fully block-local loop: zero inter-block communication
    for (int i = 0; i < 3; ++i) {
        // ---- P1: x[all 128 rows, my 32 cols] = hid @ aggW^T + aggB
        // A-frags loaded ONCE per rt, reused for both ct tiles (halves LDS reads)
        {
            const unsigned* W0 = WtH + (size_t)i * 32768;
            half8 b0[8], b1[8];
            #pragma unroll
            for (int kc = 0; kc < 8; ++kc)
                b0[kc] = ldw(W0 + (size_t)(ct0 * 8 + kc) * 256 + lane * 4);
            #pragma unroll
            for (int kc = 0; kc < 8; ++kc)
                b1[kc] = ldw(W0 + (size_t)(ct1 * 8 + kc) * 256 + lane * 4);
            const float bb0 = aggB[i * 256 + ct0 * 16 + lr];
            const float bb1 = aggB[i * 256 + ct1 * 16 + lr];
            #pragma unroll 2
            for (int rt = 0; rt < 8; ++rt) {
                half8 a[8];
                #pragma unroll
                for (int kc = 0; kc < 8; ++kc)
                    a[kc] = ldw(hid_uu + (rt * 16 + lr) * 132 + kc * 16 + lg * 4);
                f32x4 a0 = {}, a1 = {};
                #pragma unroll
                for (int kc = 0; kc < 8; ++kc) a0 = MF(a[kc], b0[kc], a0);
                #pragma unroll
                for (int kc = 0; kc < 8; ++kc) a1 = MF(a[kc], b1[kc], a1);
                float p0[4], p1[4];
                #pragma unroll
                for (int q = 0; q < 4; ++q) {
                    a0[q] += bb0; a1[q] += bb1;
                    p0[q] = __shfl_xor(a0[q], 1);
                    p1[q] = __shfl_xor(a1[q], 1);
                }
                if (!(lr & 1)) {
                    #pragma unroll
                    for (int q = 0; q < 4; ++q) {
                        x_uu[(rt * 16 + lg * 4 + q) * 132 + ct0 * 8 + (lr >> 1)] = pkh(a0[q], p0[q]);
                        x_uu[(rt * 16 + lg * 4 + q) * 132 + ct1 * 8 + (lr >> 1)] = pkh(a1[q], p1[q]);
                    }
                }
            }
            __syncthreads();
        }

        // ---- P2: p = x @ W1^T, online softmax over ALL 128 rows (in-wave)
        {
            const unsigned* W1 = WtH + (size_t)(3 + i) * 32768;
            half8 w0[8], w1[8];
            #pragma unroll
            for (int kc = 0; kc < 8; ++kc)
                w0[kc] = ldw(W1 + (size_t)(ct0 * 8 + kc) * 256 + lane * 4);
            #pragma unroll
            for (int kc = 0; kc < 8; ++kc)
                w1[kc] = ldw(W1 + (size_t)(ct1 * 8 + kc) * 256 + lane * 4);
            float M0 = -1e30f, D0 = 0.f, N0 = 0.f;
            float M1 = -1e30f, D1 = 0.f, N1 = 0.f;
            #pragma unroll 2
            for (int rt = 0; rt < 8; ++rt) {
                half8 a[8];
                #pragma unroll
                for (int kc = 0; kc < 8; ++kc)
                    a[kc] = ldw(x_uu + (rt * 16 + lr) * 132 + kc * 16 + lg * 4);
                f32x4 a0 = {}, a1 = {};
                #pragma unroll
                for (int kc = 0; kc < 8; ++kc) a0 = MF(a[kc], w0[kc], a0);
                #pragma unroll
                for (int kc = 0; kc < 8; ++kc) a1 = MF(a[kc], w1[kc], a1);
                // tile 0
                {
                    const float m4 = fmaxf(fmaxf(a0[0], a0[1]), fmaxf(a0[2], a0[3]));
                    const float Mn = fmaxf(M0, m4);
                    const float sc = __expf(M0 - Mn);
                    D0 *= sc; N0 *= sc;
                    #pragma unroll
                    for (int q = 0; q < 4; ++q) {
                        const float e = __expf(a0[q] - Mn);
                        D0 += e;
                        const unsigned xv = x_uu[(rt * 16 + lg * 4 + q) * 132 + ct0 * 8 + (lr >> 1)];
                        const h2_t xp = __builtin_bit_cast(h2_t, xv);
                        N0 += e * (float)((lr & 1) ? xp[1] : xp[0]);
                    }
                    M0 = Mn;
                }
                // tile 1
                {
                    const float m4 = fmaxf(fmaxf(a1[0], a1[1]), fmaxf(a1[2], a1[3]));
                    const float Mn = fmaxf(M1, m4);
                    const float sc = __expf(M1 - Mn);
                    D1 *= sc; N1 *= sc;
                    #pragma unroll
                    for (int q = 0; q < 4; ++q) {
                        const float e = __expf(a1[q] - Mn);
                        D1 += e;
                        const unsigned xv = x_uu[(rt * 16 + lg * 4 + q) * 132 + ct1 * 8 + (lr >> 1)];
                        const h2_t xp = __builtin_bit_cast(h2_t, xv);
                        N1 += e * (float)((lr & 1) ? xp[1] : xp[0]);
                    }
                    M1 = Mn;
                }
            }
            // combine disjoint row-sets of the 4 lg groups (lanes lr, +16, +32, +48)
            #pragma unroll
            for (int st = 16; st <= 32; st <<= 1) {
                {
                    const float Mo = __shfl_xor(M0, st), Do = __shfl_xor(D0, st), No = __shfl_xor(N0, st);
                    const float Mn = fmaxf(M0, Mo);
                    const float ea = __expf(M0 - Mn), eb = __expf(Mo - Mn);
                    D0 = D0 * ea + Do * eb; N0 = N0 * ea + No * eb; M0 = Mn;
                }
                {
                    const float Mo = __shfl_xor(M1, st), Do = __shfl_xor(D1, st), No = __shfl_xor(N1, st);
                    const float Mn = fmaxf(M1, Mo);
                    const float ea = __expf(M1 - Mn), eb = __expf(Mo - Mn);
                    D1 = D1 * ea + Do * eb; N1 = N1 * ea + No * eb; M1 = Mn;
                }
            }
            if (lg == 0) {
                aggl32[ct0 * 16 + lr] = 1.f / (1.f + __expf(-(N0 / D0)));
                aggl32[ct1 * 16 + lr] = 1.f / (1.f + __expf(-(N1 / D1)));
            }
            __syncthreads();
        }

        // ---- agg pack + U2 matvec (fdot2, old layout, rq k-split) + accl
        if (tid < 128) aggh[tid] = pkh(aggl32[2 * tid], aggl32[2 * tid + 1]);
        __syncthreads();
        {
            const unsigned* Uq = WtH + (size_t)(9 + i) * 32768;
            const int g0 = rq * 16;
            uint4 buf[8];
            #pragma unroll
            for (int j = 0; j < 8; ++j)
                buf[j] = *(const uint4*)(Uq + (size_t)(g0 + j) * 1024 + c * 4);
            float au = 0.f;
            #pragma unroll
            for (int ph = 0; ph < 2; ++ph) {
                #pragma unroll
                for (int j = 0; j < 8; ++j) {
                    const uint4 w = buf[j];
                    if (ph < 1)
                        buf[j] = *(const uint4*)(Uq + (size_t)(g0 + 8 + j) * 1024 + c * 4);
                    const uint4 a = *(const uint4*)&aggh[(g0 + ph * 8 + j) * 4];
                    au = fdot2(w.x, a.x, au);
                    au = fdot2(w.y, a.y, au);
                    au = fdot2(w.z, a.z, au);
                    au = fdot2(w.w, a.w, au);
                }
            }
            S[rq * 256 + c] = au;
        }
        __syncthreads();
        if (tid < 256) accl[tid] = S[tid] + S[256 + tid] + updB[i * 256 + tid];
        __syncthreads();

        // ---- U1 + epilogue: hid' (all 128 rows) or out (own 8 rows)
        {
            const unsigned* U1 = WtH + (size_t)(6 + i) * 32768;
            half8 u0[8], u1[8];
            #pragma unroll
            for (int kc = 0; kc < 8; ++kc)
                u0[kc] = ldw(U1 + (size_t)(ct0 * 8 + kc) * 256 + lane * 4);
            #pragma unroll
            for (int kc = 0; kc < 8; ++kc)
                u1[kc] = ldw(U1 + (size_t)(ct1 * 8 + kc) * 256 + lane * 4);
            const float av0 = accl[ct0 * 16 + lr];
            const float av1 = accl[ct1 * 16 + lr];
            #pragma unroll 2
            for (int rt = 0; rt < 8; ++rt) {
                half8 a[8];
                #pragma unroll
                for (int kc = 0; kc < 8; ++kc)
                    a[kc] = ldw(x_uu + (rt * 16 + lr) * 132 + kc * 16 + lg * 4);
                f32x4 a0 = {}, a1 = {};
                #pragma unroll
                for (int kc = 0; kc < 8; ++kc) a0 = MF(a[kc], u0[kc], a0);
                #pragma unroll
                for (int kc = 0; kc < 8; ++kc) a1 = MF(a[kc], u1[kc], a1);
                if (i < 2) {
                    float h0[4], h1[4], p0[4], p1[4];
                    #pragma unroll
                    for (int q = 0; q < 4; ++q) {
                        const float mv = msk[rt * 16 + lg * 4 + q];
                        h0[q] = (a0[q] + av0) * mv;
                        h1[q] = (a1[q] + av1) * mv;
                        p0[q] = __shfl_xor(h0[q], 1);
                        p1[q] = __shfl_xor(h1[q], 1);
                    }
                    if (!(lr & 1)) {
                        #pragma unroll
                        for (int q = 0; q < 4; ++q) {
                            hid_uu[(rt * 16 + lg * 4 + q) * 132 + ct0 * 8 + (lr >> 1)] = pkh(h0[q], p0[q]);
                            hid_uu[(rt * 16 + lg * 4 + q) * 132 + ct1 * 8 + (lr >> 1)] = pkh(h1[q], p1[q]);
                        }
                    }
                } else if (rt == (jj >> 1) && (lg >> 1) == (jj & 1)) {
                    #pragma unroll
                    for (int q = 0; q < 4; ++q) {
                        const size_t ro = (size_t)(row0 + (lg & 1) * 4 + q) * 256;
                        out[ro + ct0 * 16 + lr] = a0[q] + av0;
                        out[ro + ct1 * 16 + lr] = a1[q] + av1;
                    }
                }
            }
            if (i < 2) __syncthreads();
        }
    }
}

extern "C" void kernel_launch(void* const* d_in, const int* in_sizes, int n_in,
                              void* d_out, int out_size, void* d_ws, size_t ws_size,
                              hipStream_t stream) {
    const float* feat  = (const float*)d_in[0];
    const float* mask  = (const float*)d_in[1];
    const float* aggW  = (const float*)d_in[2];
    const float* aggB  = (const float*)d_in[3];
    const float* attnW = (const float*)d_in[4];
    // d_in[5] = attnB: cancels in softmax (constant along the s axis)
    const float* updW  = (const float*)d_in[6];
    const float* updB  = (const float*)d_in[7];

    unsigned* WtH   = (unsigned*)d_ws;                 // 12 * 32768 uints
    unsigned* flags = WtH + 12 * 32768;
    unsigned* rel   = flags + NBLK * FPAD;

    static bool smem_ok = false;
    if (!smem_ok) {
        hipFuncSetAttribute(reinterpret_cast<const void*>(fused_k),
                            hipFuncAttributeMaxDynamicSharedMemorySize, SMEM_BYTES);
        smem_ok = true;
    }

    fused_k<<<NBLK, NT, SMEM_BYTES, stream>>>(
        feat, mask, aggW, aggB, attnW, updW, updB,
        WtH, flags, rel, (float*)d_out);
}

// Round 10
// 109.378 us; speedup vs baseline: 1.3650x; 1.3650x over previous
//
#include <hip/hip_runtime.h>
#include <hip/hip_fp16.h>

#define NBLK  256
#define NPACK 192
#define NT    512
#define FPAD  16   // 64 B per flag slot

typedef _Float16 h2_t  __attribute__((ext_vector_type(2)));
typedef _Float16 half8 __attribute__((ext_vector_type(8)));
typedef float    f32x4 __attribute__((ext_vector_type(4)));

#define AG_LD(p)    __hip_atomic_load((p), __ATOMIC_RELAXED, __HIP_MEMORY_SCOPE_AGENT)
#define AG_ST(p, v) __hip_atomic_store((p), (v), __ATOMIC_RELAXED, __HIP_MEMORY_SCOPE_AGENT)

// pack two fp32 -> fp16 pair (RNE)
__device__ __forceinline__ unsigned pkh(float a, float b) {
    const __half2 h = __floats2half2_rn(a, b);
    return __builtin_bit_cast(unsigned, h);
}
// fp16-pair dot product with fp32 accumulate (v_dot2_f32_f16) — U2 matvec only
__device__ __forceinline__ float fdot2(unsigned w, unsigned a, float c) {
#if __has_builtin(__builtin_amdgcn_fdot2)
    return __builtin_amdgcn_fdot2(__builtin_bit_cast(h2_t, w),
                                  __builtin_bit_cast(h2_t, a), c, false);
#else
    const float2 fw = __half22float2(__builtin_bit_cast(__half2, w));
    const float2 fa = __half22float2(__builtin_bit_cast(__half2, a));
    return c + fw.x * fa.x + fw.y * fa.y;
#endif
}

__device__ __forceinline__ half8 ldw(const unsigned* p) {
    return __builtin_bit_cast(half8, *(const uint4*)p);
}
__device__ __forceinline__ f32x4 MF(half8 a, half8 b, f32x4 c) {
    return __builtin_amdgcn_mfma_f32_16x16x32_f16(a, b, c, 0, 0, 0);
}

// ---- per-batch barrier (R7-validated): arrive = release-store of iter no.;
// wait = threads 0..15 poll the batch's 16 flag lines. flags pre-zeroed by
// pack_k (stream order), so levels 1..3 are race-free by construction.
__device__ __forceinline__ void bar_arrive(int n, unsigned* flags, int lid) {
    __syncthreads();
    if (threadIdx.x == 0)
        __hip_atomic_store(&flags[lid * FPAD], (unsigned)n, __ATOMIC_RELEASE,
                           __HIP_MEMORY_SCOPE_AGENT);
}
__device__ __forceinline__ void bar_wait_batch(int n, unsigned* flags, int b) {
    if (threadIdx.x < 16) {
        while ((int)__hip_atomic_load(&flags[(b * 16 + threadIdx.x) * FPAD],
                                      __ATOMIC_RELAXED,
                                      __HIP_MEMORY_SCOPE_AGENT) < n)
            __builtin_amdgcn_s_sleep(1);
    }
    __syncthreads();
}

// MFMA-pack (matrices 0..8): uint idx = (t*8+kc)*256 + (g*16+lc)*4 + sl —
// lane l = g*16+lc holds col t*16+lc, k = kc*32 + g*8 + {0..7}. Identical k-map
// to the A-staging read (validated R5/R7) -> internal k relabeling cancels.
// Old pack (matrices 9..11, U2 fdot2 path): idx = (k>>3)*1024 + c*4 + ((k>>1)&3).

// ============ kernel 1: weight pack (R7-verbatim loops), zero flags ============
__global__ __launch_bounds__(NT, 2) void pack_k(
    const float* __restrict__ aggW, const float* __restrict__ attnW,
    const float* __restrict__ updW, unsigned* __restrict__ WtH,
    unsigned* __restrict__ flags)
{
    __shared__ float Tl[64][65];
    const int bb = blockIdx.x, tid = threadIdx.x;
    const int m = bb >> 4, t = bb & 15, tr = t >> 2, tc = t & 3;
    const float* src; int stride, off;
    if (m < 3)      { src = aggW  + (size_t)m * 65536;        stride = 256; off = 0;   }
    else if (m < 6) { src = attnW + (size_t)(m - 3) * 131072; stride = 512; off = 0;   }
    else if (m < 9) { src = updW  + (size_t)(m - 6) * 131072; stride = 512; off = 0;   }
    else            { src = updW  + (size_t)(m - 9) * 131072; stride = 512; off = 256; }
    unsigned* dstu = WtH + (size_t)m * 32768;
    #pragma unroll
    for (int it = 0; it < 2; ++it) {
        const int j = it * 512 + tid, row = j >> 4, q = (j & 15) * 4;
        const float4 v = *(const float4*)(src + (size_t)(tr * 64 + row) * stride + off + tc * 64 + q);
        Tl[row][q + 0] = v.x; Tl[row][q + 1] = v.y;
        Tl[row][q + 2] = v.z; Tl[row][q + 3] = v.w;
    }
    if (bb == 0)   // zero barrier flags for main_k (visible via stream order)
        for (int z = tid; z < NBLK * FPAD; z += NT) flags[z] = 0u;
    __syncthreads();
    #pragma unroll
    for (int it = 0; it < 4; ++it) {
        const int j = it * 512 + tid, cl = j >> 5, pr = j & 31;
        const unsigned val = pkh(Tl[cl][pr * 2], Tl[cl][pr * 2 + 1]);
        const int C = tr * 64 + cl, P = tc * 32 + pr;
        size_t idx;
        if (m < 9) {   // MFMA B-fragment pack
            const int ttn = C >> 4, lc = C & 15;
            const int kc = P >> 4, g = (P >> 2) & 3, sl = P & 3;
            idx = (size_t)((ttn * 8 + kc) * 256 + (g * 16 + lc) * 4 + sl);
        } else {       // old pack (U2 fdot2 path)
            idx = (size_t)(P >> 2) * 1024 + (size_t)C * 4 + (P & 3);
        }
        dstu[idx] = val;
    }
}

// Per-batch softmax combine (hoisted tree) + sigmoid + U2 matvec + updB.
__device__ __forceinline__ float phaseB(int i, int b, int c, int rq, int tid,
                                        const float* __restrict__ part,
                                        const unsigned* __restrict__ WtH,
                                        const float* __restrict__ updB,
                                        float* S, float* aggl32, unsigned* aggh) {
    const float* pbase = part + (size_t)((i & 1) * 256 + b * 16 + rq * 8) * 768;
    float m[8], d[8], nn[8];
    #pragma unroll
    for (int j = 0; j < 8; ++j) {                 // 24 loads all in flight
        const float* pp = pbase + (size_t)j * 768;
        m[j]  = AG_LD(pp + c);
        d[j]  = AG_LD(pp + 256 + c);
        nn[j] = AG_LD(pp + 512 + c);
    }
    #pragma unroll
    for (int st = 1; st < 8; st <<= 1) {          // tree combine 8 -> 1
        #pragma unroll
        for (int j = 0; j < 8; j += 2 * st) {
            const float Mn = fmaxf(m[j], m[j + st]);
            const float sa = __expf(m[j] - Mn), sb = __expf(m[j + st] - Mn);
            d[j]  = d[j] * sa + d[j + st] * sb;
            nn[j] = nn[j] * sa + nn[j + st] * sb;
            m[j]  = Mn;
        }
    }
    S[rq * 256 + c] = m[0];
    S[512 + rq * 256 + c] = d[0];
    S[1024 + rq * 256 + c] = nn[0];
    __syncthreads();
    if (rq == 0) {
        const float m0 = S[c], m1 = S[256 + c];
        const float Mx = fmaxf(m0, m1);
        const float s0 = __expf(m0 - Mx), s1 = __expf(m1 - Mx);
        const float dd = S[512 + c] * s0 + S[768 + c] * s1;
        const float nv = S[1024 + c] * s0 + S[1280 + c] * s1;
        aggl32[c] = 1.f / (1.f + __expf(-(nv / dd)));
    }
    __syncthreads();
    if (tid < 128) aggh[tid] = pkh(aggl32[2 * tid], aggl32[2 * tid + 1]);
    __syncthreads();
    // U2 matvec: OLD fp16 layout, k-split across rq halves
    const unsigned* Uq = WtH + (size_t)(9 + i) * 32768;
    const int g0 = rq * 16;
    uint4 buf[8];
    #pragma unroll
    for (int j = 0; j < 8; ++j)
        buf[j] = *(const uint4*)(Uq + (size_t)(g0 + j) * 1024 + c * 4);
    float au = 0.f;
    #pragma unroll
    for (int ph = 0; ph < 2; ++ph) {
        #pragma unroll
        for (int j = 0; j < 8; ++j) {
            const uint4 w = buf[j];
            if (ph < 1)
                buf[j] = *(const uint4*)(Uq + (size_t)(g0 + 8 + j) * 1024 + c * 4);
            const uint4 a = *(const uint4*)&aggh[(g0 + ph * 8 + j) * 4];
            au = fdot2(w.x, a.x, au);
            au = fdot2(w.y, a.y, au);
            au = fdot2(w.z, a.z, au);
            au = fdot2(w.w, a.w, au);
        }
    }
    __syncthreads();
    S[rq * 256 + c] = au;
    __syncthreads();
    return S[c] + S[256 + c] + updB[i * 256 + c];
}

// ============ kernel 2: R7 worker path verbatim (no pack, no global barrier) ====
__global__ __launch_bounds__(NT, 2) void main_k(
    const float* __restrict__ feat,   // [16][128][256]
    const float* __restrict__ mask,   // [16][128]
    const float* __restrict__ aggB,   // [3][256]
    const float* __restrict__ updB,   // [3][256]
    const unsigned* __restrict__ WtH, // 12 * 32768 uints (fp16-pair packed)
    float* __restrict__ part,         // 2 * 256 * 768
    unsigned* flags,
    float* __restrict__ out)
{
    // A-layout (validated R5/R7): row r, k-pair p2: uint idx = r*132 + p2.
    // A-frag read lane l, chunk kc: ds_read_b128 at (rt*16+(l&15))*132+kc*16+(l>>4)*4.
    __shared__ __align__(16) float ldsf[6408];
    unsigned* hid_uu = (unsigned*)ldsf;            // [0,2112)
    unsigned* x_uu   = (unsigned*)ldsf + 2112;     // [2112,4224)
    float*    accl   = ldsf + 4224;                // [4224,4480)
    float*    S      = ldsf + 4480;                // [4480,6016)
    float*    aggl32 = ldsf + 6016;                // [6016,6272)
    unsigned* aggh   = (unsigned*)ldsf + 6272;     // [6272,6400)
    float*    msk    = ldsf + 6400;                // [6400,6408)

    const int bid = blockIdx.x;
    const int tid = threadIdx.x;
    const int c   = tid & 255;
    const int rq  = tid >> 8;                 // 0..1 (phaseB k-split)
    const int wid = tid >> 6, lane = tid & 63;
    const int lr  = lane & 15, lg = lane >> 4;
    // XCD co-location: 16 blocks of a batch share bid%8 (round-robin heuristic).
    const int b   = 2 * (bid & 7) + ((bid >> 3) & 1);
    const int jj  = bid >> 4;
    const int lid = b * 16 + jj;
    const int row0 = b * 128 + jj * 8;

    // ---- P0a: stage hid0 = fp16(feat*mask) into A-layout; zero pad rows
    #pragma unroll
    for (int it = 0; it < 2; ++it) {
        const int j = it * 512 + tid, r = j >> 7, pr = j & 127;
        const float2 f = *(const float2*)(feat + (size_t)(row0 + r) * 256 + pr * 2);
        const float mv = mask[row0 + r];
        hid_uu[r * 132 + pr] = pkh(f.x * mv, f.y * mv);
    }
    for (int z = tid; z < 1056; z += NT) hid_uu[1056 + z] = 0u;
    for (int z = tid; z < 1056; z += NT) x_uu[1056 + z] = 0u;
    if (tid < 8) msk[tid] = mask[row0 + tid];
    __syncthreads();

    f32x4 xu0 = {}, xu1 = {};   // U1 results (D-layout), persist across barrier

    for (int i = 0; i < 3; ++i) {
        if (i > 0) {
            const float accU = phaseB(i - 1, b, c, rq, tid, part, WtH, updB,
                                      S, aggl32, aggh);
            if (rq == 0) accl[c] = accU;
            __syncthreads();
            // hid' = (xU1 + accU) * mask, staged from D-layout into A-layout
            #pragma unroll
            for (int tt = 0; tt < 2; ++tt) {
                const int t = wid * 2 + tt;
                const f32x4 xa = tt ? xu1 : xu0;
                const float av = accl[t * 16 + lr];
                float hv[4], pv[4];
                #pragma unroll
                for (int q = 0; q < 4; ++q)
                    hv[q] = (xa[q] + av) * msk[(lg & 1) * 4 + q];
                #pragma unroll
                for (int q = 0; q < 4; ++q) pv[q] = __shfl_xor(hv[q], 1);
                if (lg < 2 && !(lr & 1)) {
                    const int p2 = t * 8 + (lr >> 1);
                    #pragma unroll
                    for (int q = 0; q < 4; ++q)
                        hid_uu[(lg * 4 + q) * 132 + p2] = pkh(hv[q], pv[q]);
                }
            }
            __syncthreads();
        }

        f32x4 xr0, xr1;   // x (D-layout, biased) for n8

        // ---- P1: x = hid @ aggW^T + aggB via MFMA (B streamed L2->VGPR)
        {
            const unsigned* W0 = WtH + (size_t)i * 32768;
            half8 a[8];
            #pragma unroll
            for (int kc = 0; kc < 8; ++kc)
                a[kc] = ldw(hid_uu + lr * 132 + kc * 16 + lg * 4);
            #pragma unroll
            for (int tt = 0; tt < 2; ++tt) {
                const int t = wid * 2 + tt;
                f32x4 acc = {};
                #pragma unroll
                for (int kc = 0; kc < 8; ++kc)
                    acc = MF(a[kc], ldw(W0 + (size_t)(t * 8 + kc) * 256 + lane * 4), acc);
                const float bb = aggB[i * 256 + t * 16 + lr];
                #pragma unroll
                for (int q = 0; q < 4; ++q) acc[q] += bb;
                if (tt) xr1 = acc; else xr0 = acc;
                float pv[4];
                #pragma unroll
                for (int q = 0; q < 4; ++q) pv[q] = __shfl_xor(acc[q], 1);
                if (lg < 2 && !(lr & 1)) {
                    const int p2 = t * 8 + (lr >> 1);
                    #pragma unroll
                    for (int q = 0; q < 4; ++q)
                        x_uu[(lg * 4 + q) * 132 + p2] = pkh(acc[q], pv[q]);
                }
            }
            __syncthreads();
        }

        // ---- P2: W1 -> softmax partials -> arrive; U1 (hides barrier); wait
        {
            const unsigned* W1 = WtH + (size_t)(3 + i) * 32768;
            const unsigned* U1 = WtH + (size_t)(6 + i) * 32768;
            half8 a2[8];
            #pragma unroll
            for (int kc = 0; kc < 8; ++kc)
                a2[kc] = ldw(x_uu + lr * 132 + kc * 16 + lg * 4);
            float* pb = part + (size_t)((i & 1) * 256 + lid) * 768;
            #pragma unroll
            for (int tt = 0; tt < 2; ++tt) {
                const int t = wid * 2 + tt;
                f32x4 acc = {};
                #pragma unroll
                for (int kc = 0; kc < 8; ++kc)
                    acc = MF(a2[kc], ldw(W1 + (size_t)(t * 8 + kc) * 256 + lane * 4), acc);
                // per-col partials: rows 0-3 in lg==0 lanes, rows 4-7 in lg==1
                const f32x4 xa = tt ? xr1 : xr0;
                float m4 = fmaxf(fmaxf(acc[0], acc[1]), fmaxf(acc[2], acc[3]));
                const float m8 = fmaxf(m4, __shfl_xor(m4, 16));
                float d4 = 0.f, n4 = 0.f;
                #pragma unroll
                for (int q = 0; q < 4; ++q) {
                    const float e = __expf(acc[q] - m8);
                    d4 += e;
                    n4 += e * xa[q];
                }
                const float d8 = d4 + __shfl_xor(d4, 16);
                const float n8 = n4 + __shfl_xor(n4, 16);
                if (lg == 0) {
                    const int cc = t * 16 + lr;
                    AG_ST(pb + cc, m8);
                    AG_ST(pb + 256 + cc, d8);
                    AG_ST(pb + 512 + cc, n8);
                }
            }
            bar_arrive(i + 1, flags, lid);
            #pragma unroll
            for (int tt = 0; tt < 2; ++tt) {
                const int t = wid * 2 + tt;
                f32x4 acc = {};
                #pragma unroll
                for (int kc = 0; kc < 8; ++kc)
                    acc = MF(a2[kc], ldw(U1 + (size_t)(t * 8 + kc) * 256 + lane * 4), acc);
                if (tt) xu1 = acc; else xu0 = acc;
            }
            bar_wait_batch(i + 1, flags, b);   // fan-in 16, single hop
        }
    }

    // ---- final combine + epilogue: out = xU1 + accU
    {
        const float accU = phaseB(2, b, c, rq, tid, part, WtH, updB, S, aggl32, aggh);
        if (rq == 0) accl[c] = accU;
        __syncthreads();
        #pragma unroll
        for (int tt = 0; tt < 2; ++tt) {
            const int t = wid * 2 + tt;
            const f32x4 xa = tt ? xu1 : xu0;
            const float av = accl[t * 16 + lr];
            if (lg < 2) {
                #pragma unroll
                for (int q = 0; q < 4; ++q)
                    out[(size_t)(row0 + lg * 4 + q) * 256 + t * 16 + lr] = xa[q] + av;
            }
        }
    }
}

extern "C" void kernel_launch(void* const* d_in, const int* in_sizes, int n_in,
                              void* d_out, int out_size, void* d_ws, size_t ws_size,
                              hipStream_t stream) {
    const float* feat  = (const float*)d_in[0];
    const float* mask  = (const float*)d_in[1];
    const float* aggW  = (const float*)d_in[2];
    const float* aggB  = (const float*)d_in[3];
    const float* attnW = (const float*)d_in[4];
    // d_in[5] = attnB: cancels in softmax (constant along the s axis)
    const float* updW  = (const float*)d_in[6];
    const float* updB  = (const float*)d_in[7];

    unsigned* WtH = (unsigned*)d_ws;                   // 12 * 32768 uints
    float* part = (float*)(WtH + 12 * 32768);          // 2 * 256 * 768 floats
    unsigned* flags = (unsigned*)(part + 2 * 256 * 768);

    pack_k<<<NPACK, NT, 0, stream>>>(aggW, attnW, updW, WtH, flags);
    main_k<<<NBLK, NT, 0, stream>>>(feat, mask, aggB, updB, WtH, part, flags,
                                    (float*)d_out);
}